// Round 6
// baseline (118.459 us; speedup 1.0000x reference)
//
#include <hip/hip_runtime.h>

typedef __bf16 bf16x8 __attribute__((ext_vector_type(8)));
typedef float f32x4 __attribute__((ext_vector_type(4)));
typedef float f32x16 __attribute__((ext_vector_type(16)));

#define CC 256
#define HH 48
#define WW 64
#define HW (HH * WW)
#define NB 8
#define GW 21

// ---------------------------------------------------------------------------
// Prepass: BOTH inputs -> MFMA-fragment order [b][y][cblk=c>>3][x][c&7] bf16,
// so every k-loop operand load in corr is lane-linear 16B (coalesced).
// in1 scaled by 2^-8 (exact in bf16) to fold the /sumelems.
// ---------------------------------------------------------------------------
__global__ __launch_bounds__(256) void prep_kernel(const float* __restrict__ in1,
                                                   const float* __restrict__ in2,
                                                   unsigned short* __restrict__ o1,
                                                   unsigned short* __restrict__ o2)
{
    __shared__ float lds[CC * 33];
    int blk  = blockIdx.x;
    int sel  = (blk >= 768);
    int blk2 = sel ? blk - 768 : blk;
    int b  = blk2 & 7;
    int st = blk2 >> 3;                // 0..95 spatial tile (32 pixels)
    int s0 = st * 32;
    const float* src = sel ? in2 : in1;
    unsigned short* dst = sel ? o2 : o1;
    float scale = sel ? 1.0f : (1.0f / 256.0f);

    int t = threadIdx.x;
    int sidx  = t & 31;
    int cbase = t >> 5;
    const float* sb = src + (size_t)b * CC * HW + s0;
    #pragma unroll
    for (int p = 0; p < 32; ++p) {
        int c = cbase + p * 8;
        lds[c * 33 + sidx] = sb[(size_t)c * HW + sidx] * scale;
    }
    __syncthreads();

    // fragment order: [(b*48+y)*32 + cblk][x 0..63][8c]
    int y  = s0 >> 6;
    int xb = s0 & 63;                  // 0 or 32
    int s  = t & 31;
    int c8 = t >> 5;                   // 0..7
    unsigned short* db = dst + (size_t)(b * HH + y) * 32 * 64 * 8;
    #pragma unroll
    for (int it = 0; it < 4; ++it) {
        int cblk = it * 8 + c8;
        unsigned dw[4];
        #pragma unroll
        for (int d = 0; d < 4; ++d) {
            unsigned u0 = __builtin_bit_cast(unsigned, lds[(cblk * 8 + 2 * d) * 33 + s]);
            u0 += 0x7fffu + ((u0 >> 16) & 1u);
            unsigned u1 = __builtin_bit_cast(unsigned, lds[(cblk * 8 + 2 * d + 1) * 33 + s]);
            u1 += 0x7fffu + ((u1 >> 16) & 1u);
            dw[d] = (u0 >> 16) | (u1 & 0xffff0000u);
        }
        *(uint4*)(db + ((size_t)cblk * 64 + xb + s) * 8) =
            make_uint4(dw[0], dw[1], dw[2], dw[3]);
    }
}

// ---------------------------------------------------------------------------
// Main: block = (b, ysrc, jg); 4 waves handle j = 6*w + jg (balanced: every
// block has 3-4 valid j's). B row (32KB, fragment order) staged once per
// block in LDS. A streamed from global with a DEPTH-4 prefetch ring (6 loads
// in flight/wave -- R5's depth-2 starved the memory system per Little's law;
// this is the R5->R6 change), warm-up A loads hoisted above the staging
// barrier. One wave = one 64x64x256 GEMM via 32x32x16 MFMA 2x2 tiles.
// Epilogue reuses the B LDS region as per-wave D^T transpose buffers;
// nontemporal output stores. b = blk&7 pins batch to one XCD.
// Grid: 8*88*6 = 4224 blocks.
// ---------------------------------------------------------------------------
__global__ __launch_bounds__(256, 4) void corr_kernel(const unsigned short* __restrict__ in1F,
                                                      const unsigned short* __restrict__ in2F,
                                                      float* __restrict__ out)
{
    __shared__ unsigned char smem[36864];        // B-stage 32KB, then 4x9216B D^T
    unsigned short* Bl = (unsigned short*)smem;

    int blk  = blockIdx.x;
    int b    = blk & 7;                          // batch == XCD affinity
    int t2   = blk >> 3;
    int ysrc = (t2 % 88) - 20;
    int jg   = t2 / 88;                          // 0..5
    int tid  = threadIdx.x;
    int w    = tid >> 6;
    int lane = tid & 63;

    int j  = 6 * w + jg;                         // balanced packing: {jg, jg+6, jg+12, jg+18}
    int yo = ysrc - 2 * (j - 10);
    bool jvalid = (j <= 20) && (yo >= 0) && (yo < HH);

    float* orow = jvalid
        ? out + (((size_t)(b * 441 + j * GW)) * HH + yo) * WW
        : out;

    if (ysrc < 0 || ysrc >= HH) {
        // in2 source row OOB -> these 21 output rows are zero
        if (jvalid) {
            #pragma unroll
            for (int jx = 0; jx < GW; ++jx)
                __builtin_nontemporal_store(0.0f, orow + (size_t)jx * HW + lane);
        }
        return;                                  // whole block exits before barriers
    }

    int l31 = lane & 31;
    int q2  = lane >> 5;

    // A fragment base (cblk = kk*2+q2, m = mt*32+l31): lane-linear 16B
    const unsigned short* arow = jvalid
        ? in1F + (((size_t)(b * HH + yo) * 32 + q2) * 64 + l31) * 8
        : in1F;

    // ---- warm-up A loads BEFORE the staging barrier (overlap latency) ----
    bf16x8 Ab[4][2], Bb[2][2];
    if (jvalid) {
        #pragma unroll
        for (int p = 0; p < 3; ++p)
            #pragma unroll
            for (int mt = 0; mt < 2; ++mt)
                Ab[p][mt] = *(const bf16x8*)(arow + (size_t)p * 1024 + mt * 256);
    }

    // ---- stage B row (fragment order, linear 32KB copy) ----
    {
        const unsigned short* bsrc = in2F + (size_t)(b * HH + ysrc) * (32 * 64 * 8);
        #pragma unroll
        for (int it = 0; it < 8; ++it) {
            size_t off = ((size_t)it * 256 + tid) * 8;   // ushorts; 16B/thread
            *(uint4*)(Bl + off) = *(const uint4*)(bsrc + off);
        }
    }
    __syncthreads();

    f32x16 acc[2][2];
    if (jvalid) {
        const unsigned short* brow = Bl + ((size_t)q2 * 64 + l31) * 8;

        #pragma unroll
        for (int mt = 0; mt < 2; ++mt)
            #pragma unroll
            for (int nt = 0; nt < 2; ++nt)
                acc[mt][nt] = (f32x16)(0.0f);

        #pragma unroll
        for (int nt = 0; nt < 2; ++nt)
            Bb[0][nt] = *(const bf16x8*)(brow + nt * 256);

        #pragma unroll
        for (int kk = 0; kk < 16; ++kk) {
            if (kk < 13) {
                #pragma unroll
                for (int mt = 0; mt < 2; ++mt)
                    Ab[(kk + 3) & 3][mt] =
                        *(const bf16x8*)(arow + (size_t)(kk + 3) * 1024 + mt * 256);
            }
            if (kk < 15) {
                #pragma unroll
                for (int nt = 0; nt < 2; ++nt)
                    Bb[(kk + 1) & 1][nt] =
                        *(const bf16x8*)(brow + (size_t)(kk + 1) * 1024 + nt * 256);
            }
            #pragma unroll
            for (int mt = 0; mt < 2; ++mt)
                #pragma unroll
                for (int nt = 0; nt < 2; ++nt)
                    acc[mt][nt] = __builtin_amdgcn_mfma_f32_32x32x16_bf16(
                        Ab[kk & 3][mt], Bb[kk & 1][nt], acc[mt][nt], 0, 0, 0);
        }
    }

    __syncthreads();                             // B region dead; reuse for D^T

    if (!jvalid) return;

    // Epilogue: per x-half h, dump D^T into wave-private LDS, band-extract.
    // 32x32 C layout: col = l31 (n), row = (r&3) + 8*(r>>2) + 4*q2 (m).
    float* dtw = (float*)smem + w * 2304;        // [64 col][36] per wave
    #pragma unroll
    for (int h = 0; h < 2; ++h) {
        #pragma unroll
        for (int nt = 0; nt < 2; ++nt) {
            #pragma unroll
            for (int rq = 0; rq < 4; ++rq) {
                f32x4 v = { acc[h][nt][4 * rq], acc[h][nt][4 * rq + 1],
                            acc[h][nt][4 * rq + 2], acc[h][nt][4 * rq + 3] };
                *(f32x4*)(dtw + (nt * 32 + l31) * 36 + rq * 8 + q2 * 4) = v;
            }
        }
        int x = h * 32 + l31;
        #pragma unroll
        for (int jj = 0; jj < 11; ++jj) {
            int jx = 2 * jj + q2;
            if (jx >= GW) continue;
            int colx = x + 2 * (jx - 10);
            float v = (colx >= 0 && colx < WW) ? dtw[colx * 36 + l31] : 0.0f;
            __builtin_nontemporal_store(v, orow + (size_t)jx * HW + x);
        }
    }
}

extern "C" void kernel_launch(void* const* d_in, const int* in_sizes, int n_in,
                              void* d_out, int out_size, void* d_ws, size_t ws_size,
                              hipStream_t stream)
{
    (void)in_sizes; (void)n_in; (void)out_size; (void)ws_size;
    const float* in1 = (const float*)d_in[0];
    const float* in2 = (const float*)d_in[1];
    float* out = (float*)d_out;

    unsigned short* in1F = (unsigned short*)d_ws;                 // 12.6 MB
    unsigned short* in2F = in1F + (size_t)NB * HW * CC;           // 12.6 MB

    prep_kernel<<<dim3(1536), dim3(256), 0, stream>>>(in1, in2, in1F, in2F);
    corr_kernel<<<dim3(NB * 88 * 6), dim3(256), 0, stream>>>(in1F, in2F, out);
}

// Round 7
// 117.971 us; speedup vs baseline: 1.0041x; 1.0041x over previous
//
#include <hip/hip_runtime.h>

typedef __bf16 bf16x8 __attribute__((ext_vector_type(8)));
typedef float f32x4 __attribute__((ext_vector_type(4)));
typedef float f32x16 __attribute__((ext_vector_type(16)));

#define CC 256
#define HH 48
#define WW 64
#define HW (HH * WW)
#define NB 8
#define GW 21

// ---------------------------------------------------------------------------
// Prepass: BOTH inputs -> MFMA-fragment order [b][y][cblk=c>>3][x][c&7] bf16,
// so every k-loop operand load in corr is lane-linear 16B (coalesced).
// in1 scaled by 2^-8 (exact in bf16) to fold the /sumelems.
// ---------------------------------------------------------------------------
__global__ __launch_bounds__(256) void prep_kernel(const float* __restrict__ in1,
                                                   const float* __restrict__ in2,
                                                   unsigned short* __restrict__ o1,
                                                   unsigned short* __restrict__ o2)
{
    __shared__ float lds[CC * 33];
    int blk  = blockIdx.x;
    int sel  = (blk >= 768);
    int blk2 = sel ? blk - 768 : blk;
    int b  = blk2 & 7;
    int st = blk2 >> 3;                // 0..95 spatial tile (32 pixels)
    int s0 = st * 32;
    const float* src = sel ? in2 : in1;
    unsigned short* dst = sel ? o2 : o1;
    float scale = sel ? 1.0f : (1.0f / 256.0f);

    int t = threadIdx.x;
    int sidx  = t & 31;
    int cbase = t >> 5;
    const float* sb = src + (size_t)b * CC * HW + s0;
    #pragma unroll
    for (int p = 0; p < 32; ++p) {
        int c = cbase + p * 8;
        lds[c * 33 + sidx] = sb[(size_t)c * HW + sidx] * scale;
    }
    __syncthreads();

    // fragment order: [(b*48+y)*32 + cblk][x 0..63][8c]
    int y  = s0 >> 6;
    int xb = s0 & 63;                  // 0 or 32
    int s  = t & 31;
    int c8 = t >> 5;                   // 0..7
    unsigned short* db = dst + (size_t)(b * HH + y) * 32 * 64 * 8;
    #pragma unroll
    for (int it = 0; it < 4; ++it) {
        int cblk = it * 8 + c8;
        unsigned dw[4];
        #pragma unroll
        for (int d = 0; d < 4; ++d) {
            unsigned u0 = __builtin_bit_cast(unsigned, lds[(cblk * 8 + 2 * d) * 33 + s]);
            u0 += 0x7fffu + ((u0 >> 16) & 1u);
            unsigned u1 = __builtin_bit_cast(unsigned, lds[(cblk * 8 + 2 * d + 1) * 33 + s]);
            u1 += 0x7fffu + ((u1 >> 16) & 1u);
            dw[d] = (u0 >> 16) | (u1 & 0xffff0000u);
        }
        *(uint4*)(db + ((size_t)cblk * 64 + xb + s) * 8) =
            make_uint4(dw[0], dw[1], dw[2], dw[3]);
    }
}

// ---------------------------------------------------------------------------
// Main: block = (b, ysrc, jg); 4 waves handle j = 6*w + jg. B row (32KB,
// fragment order) staged once per block in LDS. A streamed from global with
// a depth-4 prefetch ring. One wave = one 64x64x256 GEMM via 32x32x16 MFMA
// 2x2 tiles. Epilogue reuses the B LDS region as per-wave D^T buffers;
// nontemporal output stores.
//
// R6->R7: grid decode is now ysrc-MAJOR (jg minor). With blk%8 -> XCD
// round-robin, the ~128 resident blocks per XCD span only ~21 consecutive
// ysrc x all jg => per-XCD live window = 61 A rows (1.95MB) + 21 B rows
// (0.67MB) < 4MB L2, instead of the entire 3.15MB batch working set (the
// R4-R6 decode had jg-major order => all 88 ysrc resident => L2 thrash =>
// the 202MB A re-read stream was served by L3 at ~14TB/s = the ~27us
// plateau). Grid: 8*88*6 = 4224 blocks.
// ---------------------------------------------------------------------------
__global__ __launch_bounds__(256, 4) void corr_kernel(const unsigned short* __restrict__ in1F,
                                                      const unsigned short* __restrict__ in2F,
                                                      float* __restrict__ out)
{
    __shared__ unsigned char smem[36864];        // B-stage 32KB, then 4x9216B D^T
    unsigned short* Bl = (unsigned short*)smem;

    int blk  = blockIdx.x;
    int b    = blk & 7;                          // batch == XCD affinity
    int t2   = blk >> 3;
    int ysrc = t2 / 6 - 20;                      // ysrc-major: locality window
    int jg   = t2 - (t2 / 6) * 6;                // 0..5
    int tid  = threadIdx.x;
    int w    = tid >> 6;
    int lane = tid & 63;

    int j  = 6 * w + jg;                         // {jg, jg+6, jg+12, jg+18}
    int yo = ysrc - 2 * (j - 10);
    bool jvalid = (j <= 20) && (yo >= 0) && (yo < HH);

    float* orow = jvalid
        ? out + (((size_t)(b * 441 + j * GW)) * HH + yo) * WW
        : out;

    if (ysrc < 0 || ysrc >= HH) {
        // in2 source row OOB -> these 21 output rows are zero
        if (jvalid) {
            #pragma unroll
            for (int jx = 0; jx < GW; ++jx)
                __builtin_nontemporal_store(0.0f, orow + (size_t)jx * HW + lane);
        }
        return;                                  // whole block exits before barriers
    }

    int l31 = lane & 31;
    int q2  = lane >> 5;

    // A fragment base (cblk = kk*2+q2, m = mt*32+l31): lane-linear 16B
    const unsigned short* arow = jvalid
        ? in1F + (((size_t)(b * HH + yo) * 32 + q2) * 64 + l31) * 8
        : in1F;

    // ---- warm-up A loads BEFORE the staging barrier (overlap latency) ----
    bf16x8 Ab[4][2], Bb[2][2];
    if (jvalid) {
        #pragma unroll
        for (int p = 0; p < 3; ++p)
            #pragma unroll
            for (int mt = 0; mt < 2; ++mt)
                Ab[p][mt] = *(const bf16x8*)(arow + (size_t)p * 1024 + mt * 256);
    }

    // ---- stage B row (fragment order, linear 32KB copy) ----
    {
        const unsigned short* bsrc = in2F + (size_t)(b * HH + ysrc) * (32 * 64 * 8);
        #pragma unroll
        for (int it = 0; it < 8; ++it) {
            size_t off = ((size_t)it * 256 + tid) * 8;   // ushorts; 16B/thread
            *(uint4*)(Bl + off) = *(const uint4*)(bsrc + off);
        }
    }
    __syncthreads();

    f32x16 acc[2][2];
    if (jvalid) {
        const unsigned short* brow = Bl + ((size_t)q2 * 64 + l31) * 8;

        #pragma unroll
        for (int mt = 0; mt < 2; ++mt)
            #pragma unroll
            for (int nt = 0; nt < 2; ++nt)
                acc[mt][nt] = (f32x16)(0.0f);

        #pragma unroll
        for (int nt = 0; nt < 2; ++nt)
            Bb[0][nt] = *(const bf16x8*)(brow + nt * 256);

        #pragma unroll
        for (int kk = 0; kk < 16; ++kk) {
            if (kk < 13) {
                #pragma unroll
                for (int mt = 0; mt < 2; ++mt)
                    Ab[(kk + 3) & 3][mt] =
                        *(const bf16x8*)(arow + (size_t)(kk + 3) * 1024 + mt * 256);
            }
            if (kk < 15) {
                #pragma unroll
                for (int nt = 0; nt < 2; ++nt)
                    Bb[(kk + 1) & 1][nt] =
                        *(const bf16x8*)(brow + (size_t)(kk + 1) * 1024 + nt * 256);
            }
            #pragma unroll
            for (int mt = 0; mt < 2; ++mt)
                #pragma unroll
                for (int nt = 0; nt < 2; ++nt)
                    acc[mt][nt] = __builtin_amdgcn_mfma_f32_32x32x16_bf16(
                        Ab[kk & 3][mt], Bb[kk & 1][nt], acc[mt][nt], 0, 0, 0);
        }
    }

    __syncthreads();                             // B region dead; reuse for D^T

    if (!jvalid) return;

    // Epilogue: per x-half h, dump D^T into wave-private LDS, band-extract.
    // 32x32 C layout: col = l31 (n), row = (r&3) + 8*(r>>2) + 4*q2 (m).
    float* dtw = (float*)smem + w * 2304;        // [64 col][36] per wave
    #pragma unroll
    for (int h = 0; h < 2; ++h) {
        #pragma unroll
        for (int nt = 0; nt < 2; ++nt) {
            #pragma unroll
            for (int rq = 0; rq < 4; ++rq) {
                f32x4 v = { acc[h][nt][4 * rq], acc[h][nt][4 * rq + 1],
                            acc[h][nt][4 * rq + 2], acc[h][nt][4 * rq + 3] };
                *(f32x4*)(dtw + (nt * 32 + l31) * 36 + rq * 8 + q2 * 4) = v;
            }
        }
        int x = h * 32 + l31;
        #pragma unroll
        for (int jj = 0; jj < 11; ++jj) {
            int jx = 2 * jj + q2;
            if (jx >= GW) continue;
            int colx = x + 2 * (jx - 10);
            float v = (colx >= 0 && colx < WW) ? dtw[colx * 36 + l31] : 0.0f;
            __builtin_nontemporal_store(v, orow + (size_t)jx * HW + x);
        }
    }
}

extern "C" void kernel_launch(void* const* d_in, const int* in_sizes, int n_in,
                              void* d_out, int out_size, void* d_ws, size_t ws_size,
                              hipStream_t stream)
{
    (void)in_sizes; (void)n_in; (void)out_size; (void)ws_size;
    const float* in1 = (const float*)d_in[0];
    const float* in2 = (const float*)d_in[1];
    float* out = (float*)d_out;

    unsigned short* in1F = (unsigned short*)d_ws;                 // 12.6 MB
    unsigned short* in2F = in1F + (size_t)NB * HW * CC;           // 12.6 MB

    prep_kernel<<<dim3(1536), dim3(256), 0, stream>>>(in1, in2, in1F, in2F);
    corr_kernel<<<dim3(NB * 88 * 6), dim3(256), 0, stream>>>(in1F, in2F, out);
}